// Round 6
// baseline (387.665 us; speedup 1.0000x reference)
//
#include <hip/hip_runtime.h>
#include <stdint.h>

typedef __attribute__((ext_vector_type(4))) int  int32x4;
typedef __attribute__((ext_vector_type(16))) int int32x16;

#define M_DIM 8192
#define N_DIM 4096
#define K_DIM 4096
#define KT    (K_DIM / 64)   // 64 K-tiles of 64B (global layout granularity)
#define KT32  (K_DIM / 32)   // 128 phases of K=32

// ---------------------------------------------------------------------------
// Global tile layout (unchanged):
//   cell(rt, kt, ks, kh, row) at byte (rt*KT + kt)*8192 + ks*4096 + kh*2048 + row*16
//   holds element (m = rt*128+row, k = kt*64 + ks*32 + kh*16 + byte), 16B/cell.
//   (rt, kt32 = kt*2+ks) view: rtbase + kt32*4096 + kh*2048 + row*16.
// ---------------------------------------------------------------------------

__device__ __forceinline__ int pack4(float4 f) {
  int a = ((int)f.x) & 255;
  int b = ((int)f.y) & 255;
  int c = ((int)f.z) & 255;
  int d = ((int)f.w) & 255;
  return a | (b << 8) | (c << 16) | (d << 24);
}

// ---------------------------------------------------------------------------
// Convert: fp32 -> i8 tiled (round-1 version, unchanged).
// ---------------------------------------------------------------------------
#define BLKS_A (64 * 16)   // rtA=64, kq=16
#define BLKS_B (32 * 16)

__global__ __launch_bounds__(256) void f32_to_i8_tiled(
    const float* __restrict__ xa, const float* __restrict__ xw,
    int4* __restrict__ dstA, int4* __restrict__ dstB)
{
  __shared__ int ts[8192];   // 32 KB, u32-addressed

  int bid = blockIdx.x;
  const float* src;
  int4* dst;
  int rt, kq;
  if (bid < BLKS_A) { src = xa; dst = dstA; rt = bid >> 4; kq = bid & 15; }
  else { bid -= BLKS_A; src = xw; dst = dstB; rt = bid >> 4; kq = bid & 15; }

  const int w = threadIdx.x >> 6;      // wave 0..3
  const int l = threadIdx.x & 63;

  const int G  = l >> 2;               // group 0..15 (= t4*4 + ks*2 + kh)
  const int gs = G & 7;                // swizzle key
  const int ldsBase = (G << 9) + (l & 3);

  const float* rowp = src + (size_t)(rt * 128 + w) * K_DIM + kq * 256 + l * 4;

#pragma unroll 4
  for (int i = 0; i < 32; ++i) {
    int row = i * 4 + w;
    float4 f = *(const float4*)(rowp + (size_t)i * 4 * K_DIM);
    ts[ldsBase + ((row ^ gs) << 2)] = pack4(f);
  }
  __syncthreads();

  // Stream out 2048 cells (32 KB); un-swizzle on the read side.
  int4* outp = dst + ((size_t)rt * KT + kq * 4) * 512;
  const int4* tsv = (const int4*)ts;
#pragma unroll
  for (int kk = 0; kk < 8; ++kk) {
    int o  = threadIdx.x + kk * 256;
    int g2 = o >> 7;
    int r2 = o & 127;
    outp[o] = tsv[(g2 << 7) + (r2 ^ (g2 & 7))];
  }
}

// ---------------------------------------------------------------------------
// int8 GEMM-BT, 256x256 tile, 8 waves (2x4), per-wave 128x64 out.
// BK=32 per phase, ring-4 LDS (64 KB), prefetch distance 3, steady vmcnt(4),
// fragments register-double-buffered (round 5).  NEW: sched_group_barrier
// pins a {MFMA 1, DS_READ 1} x6 + {MFMA 2} interleave per phase.  Round-5
// counters proved exact LDS/MFMA serialization (1205 cy/phase = 585 MFMA +
// 576 LDS + 44; MfmaUtil 48.5 = 585/1205) -- the scheduler sinks the reads
// into a cluster.  SGB forces the AITER-style 1:1 interleave so the LDS
// pipe drains under the MFMA issue backpressure.
// ---------------------------------------------------------------------------

__device__ __forceinline__ void async16(const int8_t* g, int8_t* l) {
  __builtin_amdgcn_global_load_lds(
      (const __attribute__((address_space(1))) void*)g,
      (__attribute__((address_space(3))) void*)l,
      16, 0, 0);
}

__device__ __forceinline__ int32x16 zero16() {
  int32x16 v;
#pragma unroll
  for (int i = 0; i < 16; ++i) v[i] = 0;
  return v;
}

#define LDS_BUF 16384
#define MMA(a, b, c) __builtin_amdgcn_mfma_i32_32x32x32_i8(a, b, c, 0, 0, 0)

// sched_group_barrier masks (LLVM SchedGroupMask): MFMA=0x8, DS_READ=0x100
#define SGB(m, n) __builtin_amdgcn_sched_group_barrier(m, n, 0)
#define SGB_PATTERN                                                          \
    SGB(0x008, 1); SGB(0x100, 1);                                            \
    SGB(0x008, 1); SGB(0x100, 1);                                            \
    SGB(0x008, 1); SGB(0x100, 1);                                            \
    SGB(0x008, 1); SGB(0x100, 1);                                            \
    SGB(0x008, 1); SGB(0x100, 1);                                            \
    SGB(0x008, 1); SGB(0x100, 1);                                            \
    SGB(0x008, 2)

__global__ __launch_bounds__(512, 2) void gemm_i8(
    const int8_t* __restrict__ A8, const int8_t* __restrict__ B8,
    const float* __restrict__ bias, float* __restrict__ C)
{
  __shared__ int8_t lds[4 * LDS_BUF];   // 64 KB ring: {A 8K, B 8K} x 4

  const int tid = threadIdx.x;
  const int w   = tid >> 6;            // wave 0..7
  const int l   = tid & 63;
  const int ln  = l & 31;
  const int hb  = l >> 5;
  const int wm  = w >> 2;              // 0..1  (M direction)
  const int wn  = w & 3;               // 0..3  (N direction)

  // XCD-aware swizzle: 512 blocks, 512 % 8 == 0 -> bijective chunked remap.
  const int fid = blockIdx.y * gridDim.x + blockIdx.x;
  const int swz = (fid & 7) * 64 + (fid >> 3);
  const int bn  = swz & 15;            // 16 n-tiles of 256
  const int bm  = swz >> 4;            // 32 m-tiles of 256

  // ---- staging: each wave owns chunks c0 = 2w and c0+1 (same mat/kh/h,
  //      q = 0/1 -> +1024 bytes in both global and LDS) ----
  const int c0  = w * 2;
  const int mt0 = c0 >> 3, kh0 = (c0 >> 2) & 1, h0 = (c0 >> 1) & 1;

  const int8_t* g0 = (mt0 ? B8 + (size_t)(bn * 2 + h0) * ((size_t)KT * 8192)
                          : A8 + (size_t)(bm * 2 + h0) * ((size_t)KT * 8192))
                     + kh0 * 2048 + l * 16;
  int8_t* ldsw = lds + mt0 * 8192 + kh0 * 4096 + h0 * 2048;

#define STAGE(bufOff, kt32_)                                            \
  { const int8_t* g_ = g0 + (size_t)(kt32_) * 4096;                     \
    async16(g_,        ldsw + (bufOff));                                \
    async16(g_ + 1024, ldsw + (bufOff) + 1024); }

  // ---- fragment base pointers (imm-offset folded ds_read_b128) ----
  const int8_t* pA = lds + hb * 4096 + (wm * 128 + ln) * 16;   // A rows
  const int8_t* pB = lds + 8192 + hb * 4096 + (wn * 64 + ln) * 16;

  int32x16 acc00 = zero16(), acc01 = zero16();
  int32x16 acc10 = zero16(), acc11 = zero16();
  int32x16 acc20 = zero16(), acc21 = zero16();
  int32x16 acc30 = zero16(), acc31 = zero16();

  // two fragment register sets (even 'e' / odd 'o' phases)
  int32x4 ae0, ae1, ae2, ae3, be0, be1;
  int32x4 ao0, ao1, ao2, ao3, bo0, bo1;

#define VM4 asm volatile("s_waitcnt vmcnt(4)" ::: "memory")
#define VM2 asm volatile("s_waitcnt vmcnt(2)" ::: "memory")
#define VM0 asm volatile("s_waitcnt vmcnt(0)" ::: "memory")

  // Phase: stage k+3 -> vmcnt(4) -> barrier -> [reads(k+1) into set NS |
  // MFMA(k) on set CS], with SGB pinning the 1:1 interleave.  setprio(1)
  // sits BEFORE the reads so it cannot split the scheduling region.
#define PHASE(nxOff_, STG, VMW, NS, CS)                                      \
  { STG;                                                                     \
    VMW;                                                                     \
    __builtin_amdgcn_s_barrier();                                            \
    asm volatile("" ::: "memory");                                           \
    __builtin_amdgcn_s_setprio(1);                                           \
    a##NS##0 = *(const int32x4*)(pA + (nxOff_));                             \
    a##NS##1 = *(const int32x4*)(pA + (nxOff_) + 512);                       \
    a##NS##2 = *(const int32x4*)(pA + (nxOff_) + 1024);                      \
    a##NS##3 = *(const int32x4*)(pA + (nxOff_) + 1536);                      \
    b##NS##0 = *(const int32x4*)(pB + (nxOff_));                             \
    b##NS##1 = *(const int32x4*)(pB + (nxOff_) + 512);                       \
    acc00 = MMA(a##CS##0, b##CS##0, acc00);                                  \
    acc01 = MMA(a##CS##0, b##CS##1, acc01);                                  \
    acc10 = MMA(a##CS##1, b##CS##0, acc10);                                  \
    acc11 = MMA(a##CS##1, b##CS##1, acc11);                                  \
    acc20 = MMA(a##CS##2, b##CS##0, acc20);                                  \
    acc21 = MMA(a##CS##2, b##CS##1, acc21);                                  \
    acc30 = MMA(a##CS##3, b##CS##0, acc30);                                  \
    acc31 = MMA(a##CS##3, b##CS##1, acc31);                                  \
    __builtin_amdgcn_s_setprio(0);                                           \
    SGB_PATTERN;                                                             \
  }

  // ---- prologue: stage kt32 = 0,1,2 into buf 0,1,2; read frags(0) -> E ----
  STAGE(0, 0);
  STAGE(LDS_BUF, 1);
  STAGE(2 * LDS_BUF, 2);
  VM4;                                   // stage(0) landed
  __builtin_amdgcn_s_barrier();
  asm volatile("" ::: "memory");
  ae0 = *(const int32x4*)(pA);
  ae1 = *(const int32x4*)(pA + 512);
  ae2 = *(const int32x4*)(pA + 1024);
  ae3 = *(const int32x4*)(pA + 1536);
  be0 = *(const int32x4*)(pB);
  be1 = *(const int32x4*)(pB + 512);

  // ---- main loop: phases 0..123 (buf = k%4, reg set = k%2), stage k+3 ----
  for (int kt = 0; kt < 124; kt += 4) {
    PHASE(1 * LDS_BUF, STAGE(3 * LDS_BUF, kt + 3), VM4, o, e);
    PHASE(2 * LDS_BUF, STAGE(0,           kt + 4), VM4, e, o);
    PHASE(3 * LDS_BUF, STAGE(1 * LDS_BUF, kt + 5), VM4, o, e);
    PHASE(0,           STAGE(2 * LDS_BUF, kt + 6), VM4, e, o);
  }
  // ---- phase 124 (buf0, cur E): stage last tile 127 -> buf3 ----
  PHASE(1 * LDS_BUF, STAGE(3 * LDS_BUF, 127), VM4, o, e);
  // ---- phase 125 (buf1, cur O): drain stage(126) ----
  PHASE(2 * LDS_BUF, (void)0, VM2, e, o);
  // ---- phase 126 (buf2, cur E): drain stage(127) ----
  PHASE(3 * LDS_BUF, (void)0, VM0, o, e);
  // ---- phase 127 (buf3, cur O): MFMA only ----
  __builtin_amdgcn_s_setprio(1);
  acc00 = MMA(ao0, bo0, acc00);  acc01 = MMA(ao0, bo1, acc01);
  acc10 = MMA(ao1, bo0, acc10);  acc11 = MMA(ao1, bo1, acc11);
  acc20 = MMA(ao2, bo0, acc20);  acc21 = MMA(ao2, bo1, acc21);
  acc30 = MMA(ao3, bo0, acc30);  acc31 = MMA(ao3, bo1, acc31);
  __builtin_amdgcn_s_setprio(0);

  // ---- epilogue: C/D layout (32x32): col = lane&31, row = (r&3)+8*(r>>2)+4*hb
  const int colBase = bn * 256 + wn * 64 + ln;
  const int rowBase = bm * 256 + wm * 128;
  const int bias0 = (int)bias[colBase];
  const int bias1 = (int)bias[colBase + 32];

#define CWRITE(accL, accR, ioff)                                             \
  _Pragma("unroll")                                                          \
  for (int r = 0; r < 16; ++r) {                                             \
    int rowt = (r & 3) + 8 * (r >> 2) + hb * 4;                              \
    float* cp = C + (size_t)(rowBase + (ioff) + rowt) * N_DIM + colBase;     \
    cp[0]  = (float)(accL[r] + bias0);                                       \
    cp[32] = (float)(accR[r] + bias1);                                       \
  }
  CWRITE(acc00, acc01, 0)
  CWRITE(acc10, acc11, 32)
  CWRITE(acc20, acc21, 64)
  CWRITE(acc30, acc31, 96)
}

// ---------------------------------------------------------------------------

extern "C" void kernel_launch(void* const* d_in, const int* in_sizes, int n_in,
                              void* d_out, int out_size, void* d_ws, size_t ws_size,
                              hipStream_t stream)
{
  const float* x    = (const float*)d_in[0];   // [8192, 4096]
  const float* wgt  = (const float*)d_in[1];   // [4096, 4096]
  const float* bias = (const float*)d_in[2];   // [4096]
  float* out = (float*)d_out;                  // [8192, 4096] f32

  int8_t* A8 = (int8_t*)d_ws;                          // 33.5 MB
  int8_t* B8 = A8 + (size_t)M_DIM * K_DIM;             // 16.8 MB

  f32_to_i8_tiled<<<BLKS_A + BLKS_B, 256, 0, stream>>>(
      x, wgt, (int4*)A8, (int4*)B8);
  gemm_i8<<<dim3(N_DIM / 256, M_DIM / 256), 512, 0, stream>>>(A8, B8, bias, out);
}

// Round 7
// 378.189 us; speedup vs baseline: 1.0251x; 1.0251x over previous
//
#include <hip/hip_runtime.h>
#include <stdint.h>

typedef __attribute__((ext_vector_type(4))) int  int32x4;
typedef __attribute__((ext_vector_type(16))) int int32x16;

#define M_DIM 8192
#define N_DIM 4096
#define K_DIM 4096
#define KT    (K_DIM / 64)   // 64 K-tiles of 64B (global layout granularity)
#define KT32  (K_DIM / 32)   // 128 phases of K=32

// ---------------------------------------------------------------------------
// Global tile layout (unchanged):
//   cell(rt, kt, ks, kh, row) at byte (rt*KT + kt)*8192 + ks*4096 + kh*2048 + row*16
//   holds element (m = rt*128+row, k = kt*64 + ks*32 + kh*16 + byte), 16B/cell.
//   (rt, kt32 = kt*2+ks) view: rtbase + kt32*4096 + kh*2048 + row*16.
// ---------------------------------------------------------------------------

__device__ __forceinline__ int pack4(float4 f) {
  int a = ((int)f.x) & 255;
  int b = ((int)f.y) & 255;
  int c = ((int)f.z) & 255;
  int d = ((int)f.w) & 255;
  return a | (b << 8) | (c << 16) | (d << 24);
}

// ---------------------------------------------------------------------------
// Convert: fp32 -> i8 tiled (round-1 version, unchanged).
// ---------------------------------------------------------------------------
#define BLKS_A (64 * 16)   // rtA=64, kq=16
#define BLKS_B (32 * 16)

__global__ __launch_bounds__(256) void f32_to_i8_tiled(
    const float* __restrict__ xa, const float* __restrict__ xw,
    int4* __restrict__ dstA, int4* __restrict__ dstB)
{
  __shared__ int ts[8192];   // 32 KB, u32-addressed

  int bid = blockIdx.x;
  const float* src;
  int4* dst;
  int rt, kq;
  if (bid < BLKS_A) { src = xa; dst = dstA; rt = bid >> 4; kq = bid & 15; }
  else { bid -= BLKS_A; src = xw; dst = dstB; rt = bid >> 4; kq = bid & 15; }

  const int w = threadIdx.x >> 6;      // wave 0..3
  const int l = threadIdx.x & 63;

  const int G  = l >> 2;               // group 0..15 (= t4*4 + ks*2 + kh)
  const int gs = G & 7;                // swizzle key
  const int ldsBase = (G << 9) + (l & 3);

  const float* rowp = src + (size_t)(rt * 128 + w) * K_DIM + kq * 256 + l * 4;

#pragma unroll 4
  for (int i = 0; i < 32; ++i) {
    int row = i * 4 + w;
    float4 f = *(const float4*)(rowp + (size_t)i * 4 * K_DIM);
    ts[ldsBase + ((row ^ gs) << 2)] = pack4(f);
  }
  __syncthreads();

  // Stream out 2048 cells (32 KB); un-swizzle on the read side.
  int4* outp = dst + ((size_t)rt * KT + kq * 4) * 512;
  const int4* tsv = (const int4*)ts;
#pragma unroll
  for (int kk = 0; kk < 8; ++kk) {
    int o  = threadIdx.x + kk * 256;
    int g2 = o >> 7;
    int r2 = o & 127;
    outp[o] = tsv[(g2 << 7) + (r2 ^ (g2 & 7))];
  }
}

// ---------------------------------------------------------------------------
// int8 GEMM-BT, 256x256 tile, 8 waves (2x4), per-wave 128x64 out.
// BK=32 per phase, ring-4 LDS (64 KB), prefetch distance 3, counted vmcnt,
// fragments register-double-buffered.  NEW (round 7): the ENTIRE per-phase
// cluster is volatile inline asm -- ds_read_b128 and v_mfma pinned in a 1:1
// R,M interleave the scheduler cannot undo.  Rounds 0/1/5/6 all measured the
// exact serial sum of the LDS pipe (576 cy) and MFMA pipe (585 cy) per phase
// regardless of source order or sched_group_barrier; hard-pinning is the
// remaining placement lever.  Waitcnt is fully manual: lgkmcnt(0) after each
// barrier (prev-phase frags long retired), vmcnt(4/2/0) ledger for staging.
// s_nop x3 before the epilogue covers the MFMA->VALU hazard the compiler no
// longer knows about.
// ---------------------------------------------------------------------------

__device__ __forceinline__ void async16(const int8_t* g, int8_t* l) {
  __builtin_amdgcn_global_load_lds(
      (const __attribute__((address_space(1))) void*)g,
      (__attribute__((address_space(3))) void*)l,
      16, 0, 0);
}

__device__ __forceinline__ int32x16 zero16() {
  int32x16 v;
#pragma unroll
  for (int i = 0; i < 16; ++i) v[i] = 0;
  return v;
}

#define LDS_BUF 16384

// Hard-pinned primitives (volatile asm is never reordered vs volatile asm).
#define MMA(c, a, b)                                                         \
  asm volatile("v_mfma_i32_32x32x32_i8 %0, %1, %2, %0"                       \
               : "+v"(c) : "v"(a), "v"(b))
#define DSR(dst, addr, off)                                                  \
  asm volatile("ds_read_b128 %0, %1 offset:%c2"                              \
               : "=v"(dst) : "v"(addr), "i"(off))

__global__ __launch_bounds__(512, 2) void gemm_i8(
    const int8_t* __restrict__ A8, const int8_t* __restrict__ B8,
    const float* __restrict__ bias, float* __restrict__ C)
{
  __shared__ int8_t lds[4 * LDS_BUF];   // 64 KB ring: {A 8K, B 8K} x 4

  const int tid = threadIdx.x;
  const int w   = tid >> 6;            // wave 0..7
  const int l   = tid & 63;
  const int ln  = l & 31;
  const int hb  = l >> 5;
  const int wm  = w >> 2;              // 0..1  (M direction)
  const int wn  = w & 3;               // 0..3  (N direction)

  // XCD-aware swizzle: 512 blocks, 512 % 8 == 0 -> bijective chunked remap.
  const int fid = blockIdx.y * gridDim.x + blockIdx.x;
  const int swz = (fid & 7) * 64 + (fid >> 3);
  const int bn  = swz & 15;            // 16 n-tiles of 256
  const int bm  = swz >> 4;            // 32 m-tiles of 256

  // ---- staging: each wave owns chunks c0 = 2w and c0+1 (same mat/kh/h,
  //      q = 0/1 -> +1024 bytes in both global and LDS) ----
  const int c0  = w * 2;
  const int mt0 = c0 >> 3, kh0 = (c0 >> 2) & 1, h0 = (c0 >> 1) & 1;

  const int8_t* g0 = (mt0 ? B8 + (size_t)(bn * 2 + h0) * ((size_t)KT * 8192)
                          : A8 + (size_t)(bm * 2 + h0) * ((size_t)KT * 8192))
                     + kh0 * 2048 + l * 16;
  int8_t* ldsw = lds + mt0 * 8192 + kh0 * 4096 + h0 * 2048;

#define STAGE(bufOff, kt32_)                                            \
  { const int8_t* g_ = g0 + (size_t)(kt32_) * 4096;                     \
    async16(g_,        ldsw + (bufOff));                                \
    async16(g_ + 1024, ldsw + (bufOff) + 1024); }

  // ---- fragment LDS base addresses as 32-bit LDS byte offsets ----
  const unsigned aAddr = (unsigned)(size_t)
      (__attribute__((address_space(3))) int8_t*)
      (lds + hb * 4096 + (wm * 128 + ln) * 16);
  const unsigned bAddr = (unsigned)(size_t)
      (__attribute__((address_space(3))) int8_t*)
      (lds + 8192 + hb * 4096 + (wn * 64 + ln) * 16);

  int32x16 acc00 = zero16(), acc01 = zero16();
  int32x16 acc10 = zero16(), acc11 = zero16();
  int32x16 acc20 = zero16(), acc21 = zero16();
  int32x16 acc30 = zero16(), acc31 = zero16();

  // two fragment register sets (even 'e' / odd 'o' phases)
  int32x4 ae0, ae1, ae2, ae3, be0, be1;
  int32x4 ao0, ao1, ao2, ao3, bo0, bo1;

#define VM4 asm volatile("s_waitcnt vmcnt(4)" ::: "memory")
#define VM2 asm volatile("s_waitcnt vmcnt(2)" ::: "memory")
#define VM0 asm volatile("s_waitcnt vmcnt(0)" ::: "memory")

  // Phase: stage k+3 -> vmcnt -> barrier -> lgkmcnt(0) (prev-phase frags
  // retired) -> pinned 1:1 interleave: reads(k+1, set NS) lead, MFMAs(k,
  // set CS) fill.  nx_ is the LDS-buffer byte offset of tile k+1.
#define PHASE(nx_, STG, VMW, NS, CS)                                         \
  { STG;                                                                     \
    VMW;                                                                     \
    __builtin_amdgcn_s_barrier();                                            \
    asm volatile("s_waitcnt lgkmcnt(0)" ::: "memory");                       \
    __builtin_amdgcn_sched_barrier(0);                                       \
    __builtin_amdgcn_s_setprio(1);                                           \
    DSR(a##NS##0, aAddr, (nx_) + 0);                                         \
    MMA(acc00, a##CS##0, b##CS##0);                                          \
    DSR(a##NS##1, aAddr, (nx_) + 512);                                       \
    MMA(acc01, a##CS##0, b##CS##1);                                          \
    DSR(a##NS##2, aAddr, (nx_) + 1024);                                      \
    MMA(acc10, a##CS##1, b##CS##0);                                          \
    DSR(a##NS##3, aAddr, (nx_) + 1536);                                      \
    MMA(acc11, a##CS##1, b##CS##1);                                          \
    DSR(b##NS##0, bAddr, (nx_) + 0);                                         \
    MMA(acc20, a##CS##2, b##CS##0);                                          \
    DSR(b##NS##1, bAddr, (nx_) + 512);                                       \
    MMA(acc21, a##CS##2, b##CS##1);                                          \
    MMA(acc30, a##CS##3, b##CS##0);                                          \
    MMA(acc31, a##CS##3, b##CS##1);                                          \
    __builtin_amdgcn_s_setprio(0);                                           \
  }

  // ---- prologue: stage kt32 = 0,1,2 into buf 0,1,2; read frags(0) -> E ----
  STAGE(0, 0);
  STAGE(LDS_BUF, 1);
  STAGE(2 * LDS_BUF, 2);
  VM4;                                   // stage(0) landed
  __builtin_amdgcn_s_barrier();
  asm volatile("" ::: "memory");
  DSR(ae0, aAddr, 0);
  DSR(ae1, aAddr, 512);
  DSR(ae2, aAddr, 1024);
  DSR(ae3, aAddr, 1536);
  DSR(be0, bAddr, 0);
  DSR(be1, bAddr, 512);

  // ---- main loop: phases 0..123 (buf = k%4, reg set = k%2), stage k+3 ----
  for (int kt = 0; kt < 124; kt += 4) {
    PHASE(1 * LDS_BUF, STAGE(3 * LDS_BUF, kt + 3), VM4, o, e);
    PHASE(2 * LDS_BUF, STAGE(0,           kt + 4), VM4, e, o);
    PHASE(3 * LDS_BUF, STAGE(1 * LDS_BUF, kt + 5), VM4, o, e);
    PHASE(0,           STAGE(2 * LDS_BUF, kt + 6), VM4, e, o);
  }
  // ---- phase 124 (buf0, cur E): stage last tile 127 -> buf3 ----
  PHASE(1 * LDS_BUF, STAGE(3 * LDS_BUF, 127), VM4, o, e);
  // ---- phase 125 (buf1, cur O): drain stage(126) ----
  PHASE(2 * LDS_BUF, (void)0, VM2, e, o);
  // ---- phase 126 (buf2, cur E): drain stage(127) ----
  PHASE(3 * LDS_BUF, (void)0, VM0, o, e);
  // ---- phase 127 (buf3, cur O): MFMA only ----
  asm volatile("s_waitcnt lgkmcnt(0)" ::: "memory");
  __builtin_amdgcn_s_setprio(1);
  MMA(acc00, ao0, bo0);  MMA(acc01, ao0, bo1);
  MMA(acc10, ao1, bo0);  MMA(acc11, ao1, bo1);
  MMA(acc20, ao2, bo0);  MMA(acc21, ao2, bo1);
  MMA(acc30, ao3, bo0);  MMA(acc31, ao3, bo1);
  __builtin_amdgcn_s_setprio(0);
  // MFMA -> VALU hazard cover (compiler can't see MFMAs inside asm).
  asm volatile("s_nop 7\n\ts_nop 7\n\ts_nop 7" ::: );

  // ---- epilogue: C/D layout (32x32): col = lane&31, row = (r&3)+8*(r>>2)+4*hb
  const int colBase = bn * 256 + wn * 64 + ln;
  const int rowBase = bm * 256 + wm * 128;
  const int bias0 = (int)bias[colBase];
  const int bias1 = (int)bias[colBase + 32];

#define CWRITE(accL, accR, ioff)                                             \
  _Pragma("unroll")                                                          \
  for (int r = 0; r < 16; ++r) {                                             \
    int rowt = (r & 3) + 8 * (r >> 2) + hb * 4;                              \
    float* cp = C + (size_t)(rowBase + (ioff) + rowt) * N_DIM + colBase;     \
    cp[0]  = (float)(accL[r] + bias0);                                       \
    cp[32] = (float)(accR[r] + bias1);                                       \
  }
  CWRITE(acc00, acc01, 0)
  CWRITE(acc10, acc11, 32)
  CWRITE(acc20, acc21, 64)
  CWRITE(acc30, acc31, 96)
}

// ---------------------------------------------------------------------------

extern "C" void kernel_launch(void* const* d_in, const int* in_sizes, int n_in,
                              void* d_out, int out_size, void* d_ws, size_t ws_size,
                              hipStream_t stream)
{
  const float* x    = (const float*)d_in[0];   // [8192, 4096]
  const float* wgt  = (const float*)d_in[1];   // [4096, 4096]
  const float* bias = (const float*)d_in[2];   // [4096]
  float* out = (float*)d_out;                  // [8192, 4096] f32

  int8_t* A8 = (int8_t*)d_ws;                          // 33.5 MB
  int8_t* B8 = A8 + (size_t)M_DIM * K_DIM;             // 16.8 MB

  f32_to_i8_tiled<<<BLKS_A + BLKS_B, 256, 0, stream>>>(
      x, wgt, (int4*)A8, (int4*)B8);
  gemm_i8<<<dim3(N_DIM / 256, M_DIM / 256), 512, 0, stream>>>(A8, B8, bias, out);
}